// Round 4
// baseline (321.839 us; speedup 1.0000x reference)
//
#include <hip/hip_runtime.h>
#include <hip/hip_bf16.h>
#include <math.h>

#define N_NODES 100000
#define N_EDGES 3200000
#define NB 16           // nodes per block-iteration (node phase)
#define EPSV 1e-8f

#define NBUCK 1563                 // ceil(100000 / 64) buckets of 64 nodes
#define NCHUNK 512                 // edge chunks
#define CHUNK_E (N_EDGES / NCHUNK) // 6250 edges per chunk

typedef __attribute__((ext_vector_type(8))) short short8;
typedef __attribute__((ext_vector_type(4))) float f32x4;

static __device__ __forceinline__ unsigned short f2bf(float x) {
  union { float f; unsigned int u; } c; c.f = x;
  unsigned int r = c.u + 0x7fff + ((c.u >> 16) & 1);   // RNE
  return (unsigned short)(r >> 16);
}

// ---------------- A: per-chunk histogram of row>>6 (LDS atomics only) -------
__global__ __launch_bounds__(256) void hist_kernel(const int* __restrict__ row,
                                                   int* __restrict__ hist) {
  __shared__ int lh[NBUCK];
  for (int i = threadIdx.x; i < NBUCK; i += 256) lh[i] = 0;
  __syncthreads();
  const int c = blockIdx.x;
  const int e1 = c * CHUNK_E + CHUNK_E;
  for (int e = c * CHUNK_E + threadIdx.x; e < e1; e += 256)
    atomicAdd(&lh[row[e] >> 6], 1);
  __syncthreads();
  for (int i = threadIdx.x; i < NBUCK; i += 256)
    hist[(size_t)c * NBUCK + i] = lh[i];
}

// ---------------- B1: exclusive scan over chunks, per bucket ----------------
__global__ __launch_bounds__(256) void scanc_kernel(int* __restrict__ hist,
                                                    int* __restrict__ total) {
  __shared__ int s[2][NCHUNK];
  const int b = blockIdx.x;
  const int t = threadIdx.x;
  s[0][t]       = hist[(size_t)t * NBUCK + b];
  s[0][t + 256] = hist[(size_t)(t + 256) * NBUCK + b];
  __syncthreads();
  int src = 0;
  for (int off = 1; off < NCHUNK; off <<= 1) {
    int dst = src ^ 1;
    for (int i = t; i < NCHUNK; i += 256)
      s[dst][i] = s[src][i] + ((i >= off) ? s[src][i - off] : 0);
    __syncthreads();
    src = dst;
  }
  hist[(size_t)t * NBUCK + b]         = (t == 0) ? 0 : s[src][t - 1];
  hist[(size_t)(t + 256) * NBUCK + b] = s[src][t + 255];
  if (t == 0) total[b] = s[src][NCHUNK - 1];
}

// ---------------- B2: exclusive scan over buckets ---------------------------
__global__ __launch_bounds__(256) void scanb_kernel(const int* __restrict__ total,
                                                    int* __restrict__ base) {
  __shared__ int s[2][2048];
  const int t = threadIdx.x;
  for (int i = t; i < 2048; i += 256) s[0][i] = (i < NBUCK) ? total[i] : 0;
  __syncthreads();
  int src = 0;
  for (int off = 1; off < 2048; off <<= 1) {
    int dst = src ^ 1;
    for (int i = t; i < 2048; i += 256)
      s[dst][i] = s[src][i] + ((i >= off) ? s[src][i - off] : 0);
    __syncthreads();
    src = dst;
  }
  for (int i = t; i <= NBUCK; i += 256) base[i] = (i == 0) ? 0 : s[src][i - 1];
}

// ---------------- C: scatter packed edge ids into bucket order --------------
__global__ __launch_bounds__(256) void scatter_kernel(const int* __restrict__ row,
                                                      const int* __restrict__ hist,
                                                      const int* __restrict__ base,
                                                      int* __restrict__ sorted) {
  __shared__ int off[NBUCK];
  const int c = blockIdx.x;
  for (int i = threadIdx.x; i < NBUCK; i += 256)
    off[i] = hist[(size_t)c * NBUCK + i] + base[i];
  __syncthreads();
  const int e1 = c * CHUNK_E + CHUNK_E;
  for (int e = c * CHUNK_E + threadIdx.x; e < e1; e += 256) {
    int r = row[e];
    int p = atomicAdd(&off[r >> 6], 1);
    sorted[p] = (e << 6) | (r & 63);
  }
}

// ---------------- D: per-bucket reduce, cooperative 9-lane gather -----------
__global__ __launch_bounds__(256) void reduce_kernel(const int* __restrict__ sorted,
                                                     const int* __restrict__ base,
                                                     const float* __restrict__ frames,
                                                     float* __restrict__ acc) {
  __shared__ float a[64 * 11];   // stride 11 -> odd bank stride
  const int b = blockIdx.x;
  for (int i = threadIdx.x; i < 64 * 11; i += 256) a[i] = 0.f;
  __syncthreads();
  const int wid = threadIdx.x >> 6, lane = threadIdx.x & 63;
  const int eg = lane / 9;          // edge-group within wave: 0..6 (lane 63 idle)
  const int k  = lane - eg * 9;     // frame component 0..8
  const bool active = lane < 63;
  const int p0 = base[b], p1 = base[b + 1];
  // wave `wid` covers edges [start, start+7) each iteration; block covers 28
  for (int start = p0 + wid * 7; start < p1; start += 28) {
    int p = start + eg;
    if (active && p < p1) {
      int pk = sorted[p];                       // 9 lanes same addr -> 1 txn
      int node = pk & 63;
      float v = frames[(size_t)(pk >> 6) * 9 + k];  // 7 dense 36B regions/instr
      atomicAdd(a + node * 11 + k, v);
      if (k == 0) atomicAdd(a + node * 11 + 9, 1.0f);
    }
  }
  __syncthreads();
  const int n0 = b << 6;
  for (int i = threadIdx.x; i < 64 * 10; i += 256) {
    int node = i / 10, kk = i - node * 10;
    int n = n0 + node;
    if (n < N_NODES) acc[(size_t)n * 10 + kk] = a[node * 11 + kk];
  }
}

// ---------------- prep: pre-swizzle Ws/Wg into MFMA B-fragment layout -------
__global__ __launch_bounds__(256) void prep_kernel(const float* __restrict__ Ws,
                                                   const float* __restrict__ Wg,
                                                   unsigned short* __restrict__ wsWs,
                                                   unsigned short* __restrict__ wsWg) {
  int idx = blockIdx.x * 256 + threadIdx.x;     // 80 blocks -> 20480 threads
  if (idx < 8 * 5 * 512) {                      // ((nt*5+kk)*64 + l)*8 + j
    int j = idx & 7, l = (idx >> 3) & 63, t = idx >> 9;
    int nt = t / 5, kk = t - nt * 5;
    int o = nt * 16 + (l & 15);
    int m = kk * 32 + ((l >> 4) << 3) + j;
    wsWs[idx] = (m < 153) ? f2bf(Ws[o * 153 + m]) : (unsigned short)0;
  }
  if (idx < 4 * 512) {                          // ((kk*64 + l)*8 + j)
    int j = idx & 7, l = (idx >> 3) & 63, kk = idx >> 9;
    int v = l & 15;
    int m = kk * 32 + ((l >> 4) << 3) + j;
    wsWg[idx] = f2bf(Wg[v * 128 + m]);
  }
}

// ---------------- node phase: MFMA for big matvec + gate --------------------
__global__ __launch_bounds__(256, 4) void node_kernel(
    const float* __restrict__ scalar_rep,   // [N][128]
    const float* __restrict__ vrep,         // [N][16][3]
    const float* __restrict__ Wd,           // [16][16]
    const float* __restrict__ Wf,           // [3][16]
    const float* __restrict__ bs,           // [128]
    const float* __restrict__ Wu,           // [16][16]
    const float* __restrict__ bg,           // [16]
    const unsigned short* __restrict__ wsWs,// pre-swizzled B-frags [8][5][64][8]
    const unsigned short* __restrict__ wsWg,// pre-swizzled B-frags [4][64][8]
    const float* __restrict__ acc,          // [N][10]
    float* __restrict__ out_s,              // [N][128]
    float* __restrict__ out_v) {            // [N][16][3]
  __shared__ alignas(16) unsigned short s_mergedb[16 * 168];  // bf16, pad->168
  __shared__ alignas(16) unsigned short s_sfb[16 * 136];      // bf16 silu
  __shared__ float s_vrep[16][48];
  __shared__ float s_vh[16][48];
  __shared__ float s_vdf[16][12];
  __shared__ float s_gate[16][16];
  __shared__ float s_WdT[256], s_WuT[256], s_Wf[48], s_bs[128], s_bg[16];

  const int tid = threadIdx.x;
  {
    int a = tid >> 4, b = tid & 15;
    s_WdT[b * 16 + a] = Wd[tid];
    s_WuT[b * 16 + a] = Wu[tid];
  }
  if (tid < 48) s_Wf[tid] = Wf[tid];
  if (tid < 128) s_bs[tid] = bs[tid];
  if (tid < 16) s_bg[tid] = bg[tid];
  if (tid < 240) {                       // zero merged pad cols 153..167
    int r = tid / 15, c = 153 + tid % 15;
    s_mergedb[r * 168 + c] = 0;
  }

  const int i4 = tid >> 4, j4 = tid & 15;
  const int wid = tid >> 6, lane = tid & 63;
  const int lr = lane & 15, lk = lane >> 4;

  const float4* scalar4 = (const float4*)scalar_rep;
  const float4* vrep4 = (const float4*)vrep;

  for (int g = blockIdx.x; g < N_NODES / NB; g += gridDim.x) {
    const int n0 = g * NB;
    __syncthreads();   // previous iteration consumers done
    // stage scalar_rep -> bf16 merged[.,0:128]
    for (int idx = tid; idx < 512; idx += 256) {
      float4 v = scalar4[(size_t)n0 * 32 + idx];
      int r = idx >> 5, c4 = idx & 31;
      unsigned short* d = s_mergedb + r * 168 + c4 * 4;
      d[0] = f2bf(v.x); d[1] = f2bf(v.y); d[2] = f2bf(v.z); d[3] = f2bf(v.w);
    }
    // stage vector_rep f32
    for (int idx = tid; idx < 192; idx += 256)
      ((float4*)s_vrep)[idx] = vrep4[(size_t)n0 * 12 + idx];
    __syncthreads();
    // vh + vnorm
    {
      float a0 = 0.f, a1 = 0.f, a2 = 0.f;
#pragma unroll
      for (int v = 0; v < 16; ++v) {
        float w = s_WdT[v * 16 + j4];
        a0 += s_vrep[i4][v * 3 + 0] * w;
        a1 += s_vrep[i4][v * 3 + 1] * w;
        a2 += s_vrep[i4][v * 3 + 2] * w;
      }
      s_vh[i4][j4]      = a0;
      s_vh[i4][16 + j4] = a1;
      s_vh[i4][32 + j4] = a2;
      s_mergedb[i4 * 168 + 128 + j4] = f2bf(sqrtf(a0 * a0 + a1 * a1 + a2 * a2 + EPSV));
    }
    // vdf
    if (j4 < 9) {
      int t = j4 / 3, f = j4 - t * 3;
      float a = 0.f;
#pragma unroll
      for (int v = 0; v < 16; ++v)
        a += s_vrep[i4][v * 3 + t] * s_Wf[f * 16 + v];
      s_vdf[i4][j4] = a;
    }
    __syncthreads();
    // scalar_hidden -> merged[.,144:153]
    if (j4 < 9) {
      int f = j4 / 3, s = j4 - f * 3;
      const float* a = acc + (size_t)(n0 + i4) * 10;
      float c = fmaxf(a[9], 1.0f);
      float sum = a[s * 3 + 0] * s_vdf[i4][0 + f] +
                  a[s * 3 + 1] * s_vdf[i4][3 + f] +
                  a[s * 3 + 2] * s_vdf[i4][6 + f];
      s_mergedb[i4 * 168 + 144 + j4] = f2bf(sum / c);
    }
    __syncthreads();
    // big MFMA: merged[16x160] @ WsT[160x128]; wave wid owns N-tiles 2w,2w+1
    {
      const int nt0 = wid * 2;
      short8 afrag[5];
#pragma unroll
      for (int kk = 0; kk < 5; ++kk)
        afrag[kk] = *(const short8*)(s_mergedb + lr * 168 + kk * 32 + lk * 8);
      float b0v = s_bs[nt0 * 16 + lr], b1v = s_bs[nt0 * 16 + 16 + lr];
      f32x4 acc0 = {b0v, b0v, b0v, b0v};
      f32x4 acc1 = {b1v, b1v, b1v, b1v};
#pragma unroll
      for (int kk = 0; kk < 5; ++kk) {
        short8 bf0 = *(const short8*)(wsWs + (((nt0 * 5 + kk) << 6) + lane) * 8);
        short8 bf1 = *(const short8*)(wsWs + ((((nt0 + 1) * 5 + kk) << 6) + lane) * 8);
        acc0 = __builtin_amdgcn_mfma_f32_16x16x32_bf16(afrag[kk], bf0, acc0, 0, 0, 0);
        acc1 = __builtin_amdgcn_mfma_f32_16x16x32_bf16(afrag[kk], bf1, acc1, 0, 0, 0);
      }
#pragma unroll
      for (int j = 0; j < 4; ++j) {
        int node = lk * 4 + j;
        float x0 = acc0[j];
        float sf0 = x0 / (1.0f + __expf(-x0));
        out_s[(size_t)(n0 + node) * 128 + nt0 * 16 + lr] = sf0;
        s_sfb[node * 136 + nt0 * 16 + lr] = f2bf(sf0);
        float x1 = acc1[j];
        float sf1 = x1 / (1.0f + __expf(-x1));
        out_s[(size_t)(n0 + node) * 128 + nt0 * 16 + 16 + lr] = sf1;
        s_sfb[node * 136 + nt0 * 16 + 16 + lr] = f2bf(sf1);
      }
    }
    __syncthreads();
    // gate MFMA on wave 0: sf[16x128] @ WgT[128x16]
    if (wid == 0) {
      float gb = s_bg[lr];
      f32x4 gacc = {gb, gb, gb, gb};
#pragma unroll
      for (int kk = 0; kk < 4; ++kk) {
        short8 ga = *(const short8*)(s_sfb + lr * 136 + kk * 32 + lk * 8);
        short8 gw = *(const short8*)(wsWg + (((kk << 6) + lane) * 8));
        gacc = __builtin_amdgcn_mfma_f32_16x16x32_bf16(ga, gw, gacc, 0, 0, 0);
      }
#pragma unroll
      for (int j = 0; j < 4; ++j) {
        int node = lk * 4 + j;
        s_gate[node][lr] = 1.0f / (1.0f + __expf(-gacc[j]));
      }
    }
    __syncthreads();
    // v_up + gated output
    {
      float b0 = 0.f, b1 = 0.f, b2 = 0.f;
#pragma unroll
      for (int h = 0; h < 16; ++h) {
        float w = s_WuT[h * 16 + j4];
        b0 += s_vh[i4][h]      * w;
        b1 += s_vh[i4][16 + h] * w;
        b2 += s_vh[i4][32 + h] * w;
      }
      float gt = s_gate[i4][j4];
      size_t basep = (size_t)(n0 + i4) * 48 + (size_t)j4 * 3;
      out_v[basep + 0] = b0 * gt;
      out_v[basep + 1] = b1 * gt;
      out_v[basep + 2] = b2 * gt;
    }
  }
}

extern "C" void kernel_launch(void* const* d_in, const int* in_sizes, int n_in,
                              void* d_out, int out_size, void* d_ws, size_t ws_size,
                              hipStream_t stream) {
  const float* scalar_rep = (const float*)d_in[0];
  const float* vector_rep = (const float*)d_in[1];
  const float* frames     = (const float*)d_in[2];
  const float* W_down     = (const float*)d_in[3];
  const float* W_frames   = (const float*)d_in[4];
  const float* W_scalar   = (const float*)d_in[5];
  const float* b_scalar   = (const float*)d_in[6];
  const float* W_up       = (const float*)d_in[7];
  const float* W_gate     = (const float*)d_in[8];
  const float* b_gate     = (const float*)d_in[9];
  const int*   edge_index = (const int*)d_in[10];   // [2][E], row = first E

  float* out = (float*)d_out;

  // workspace layout (all regions multiples of 16 ints -> 16B aligned)
  int* ws = (int*)d_ws;
  int*   hist   = ws;                                  // 512*1563 = 800256
  int*   total  = hist + 800256;                       // 1600
  int*   base   = total + 1600;                        // 1600
  int*   sorted = base + 1600;                         // 3200000
  float* acc    = (float*)(sorted + 3200000);          // 1000000 floats
  unsigned short* wsWs = (unsigned short*)(acc + 1000000);  // 20480 bf16
  unsigned short* wsWg = wsWs + 20480;                      // 2048 bf16

  prep_kernel   <<<80,     256, 0, stream>>>(W_scalar, W_gate, wsWs, wsWg);
  hist_kernel   <<<NCHUNK, 256, 0, stream>>>(edge_index, hist);
  scanc_kernel  <<<NBUCK,  256, 0, stream>>>(hist, total);
  scanb_kernel  <<<1,      256, 0, stream>>>(total, base);
  scatter_kernel<<<NCHUNK, 256, 0, stream>>>(edge_index, hist, base, sorted);
  reduce_kernel <<<NBUCK,  256, 0, stream>>>(sorted, base, frames, acc);

  node_kernel<<<768, 256, 0, stream>>>(
      scalar_rep, vector_rep, W_down, W_frames, b_scalar,
      W_up, b_gate, wsWs, wsWg, acc,
      out, out + (size_t)N_NODES * 128);
}

// Round 5
// 316.034 us; speedup vs baseline: 1.0184x; 1.0184x over previous
//
#include <hip/hip_runtime.h>
#include <hip/hip_bf16.h>
#include <math.h>

#define N_NODES 100000
#define N_EDGES 3200000
#define NB 16           // nodes per block-iteration (node phase)
#define EPSV 1e-8f

#define NBUCK 1563                 // ceil(100000 / 64) buckets of 64 nodes
#define NCHUNK 512                 // edge chunks
#define CHUNK_E (N_EDGES / NCHUNK) // 6250 edges per chunk

typedef __attribute__((ext_vector_type(8))) short short8;
typedef __attribute__((ext_vector_type(4))) float f32x4;

static __device__ __forceinline__ unsigned short f2bf(float x) {
  union { float f; unsigned int u; } c; c.f = x;
  unsigned int r = c.u + 0x7fff + ((c.u >> 16) & 1);   // RNE
  return (unsigned short)(r >> 16);
}

// ---------------- A: per-chunk histogram of row>>6 (LDS atomics only) -------
__global__ __launch_bounds__(256) void hist_kernel(const int* __restrict__ row,
                                                   int* __restrict__ hist) {
  __shared__ int lh[NBUCK];
  for (int i = threadIdx.x; i < NBUCK; i += 256) lh[i] = 0;
  __syncthreads();
  const int c = blockIdx.x;
  const int e1 = c * CHUNK_E + CHUNK_E;
  for (int e = c * CHUNK_E + threadIdx.x; e < e1; e += 256)
    atomicAdd(&lh[row[e] >> 6], 1);
  __syncthreads();
  for (int i = threadIdx.x; i < NBUCK; i += 256)
    hist[(size_t)c * NBUCK + i] = lh[i];
}

// ---------------- B1: exclusive scan over chunks, per bucket ----------------
__global__ __launch_bounds__(256) void scanc_kernel(int* __restrict__ hist,
                                                    int* __restrict__ total) {
  __shared__ int s[2][NCHUNK];
  const int b = blockIdx.x;
  const int t = threadIdx.x;
  s[0][t]       = hist[(size_t)t * NBUCK + b];
  s[0][t + 256] = hist[(size_t)(t + 256) * NBUCK + b];
  __syncthreads();
  int src = 0;
  for (int off = 1; off < NCHUNK; off <<= 1) {
    int dst = src ^ 1;
    for (int i = t; i < NCHUNK; i += 256)
      s[dst][i] = s[src][i] + ((i >= off) ? s[src][i - off] : 0);
    __syncthreads();
    src = dst;
  }
  hist[(size_t)t * NBUCK + b]         = (t == 0) ? 0 : s[src][t - 1];
  hist[(size_t)(t + 256) * NBUCK + b] = s[src][t + 255];
  if (t == 0) total[b] = s[src][NCHUNK - 1];
}

// ---------------- B2: exclusive scan over buckets ---------------------------
__global__ __launch_bounds__(256) void scanb_kernel(const int* __restrict__ total,
                                                    int* __restrict__ base) {
  __shared__ int s[2][2048];
  const int t = threadIdx.x;
  for (int i = t; i < 2048; i += 256) s[0][i] = (i < NBUCK) ? total[i] : 0;
  __syncthreads();
  int src = 0;
  for (int off = 1; off < 2048; off <<= 1) {
    int dst = src ^ 1;
    for (int i = t; i < 2048; i += 256)
      s[dst][i] = s[src][i] + ((i >= off) ? s[src][i - off] : 0);
    __syncthreads();
    src = dst;
  }
  for (int i = t; i <= NBUCK; i += 256) base[i] = (i == 0) ? 0 : s[src][i - 1];
}

// ---------------- C: scatter packed edge ids into bucket order --------------
__global__ __launch_bounds__(256) void scatter_kernel(const int* __restrict__ row,
                                                      const int* __restrict__ hist,
                                                      const int* __restrict__ base,
                                                      int* __restrict__ sorted) {
  __shared__ int off[NBUCK];
  const int c = blockIdx.x;
  for (int i = threadIdx.x; i < NBUCK; i += 256)
    off[i] = hist[(size_t)c * NBUCK + i] + base[i];
  __syncthreads();
  const int e1 = c * CHUNK_E + CHUNK_E;
  for (int e = c * CHUNK_E + threadIdx.x; e < e1; e += 256) {
    int r = row[e];
    int p = atomicAdd(&off[r >> 6], 1);
    sorted[p] = (e << 6) | (r & 63);
  }
}

// ------- D: per-bucket reduce, 9-lane gather + 8-deep software pipeline -----
__global__ __launch_bounds__(256) void reduce_kernel(const int* __restrict__ sorted,
                                                     const int* __restrict__ base,
                                                     const float* __restrict__ frames,
                                                     float* __restrict__ acc) {
  __shared__ float a[64 * 11];   // stride 11 -> odd bank stride
  const int b = blockIdx.x;
  for (int i = threadIdx.x; i < 64 * 11; i += 256) a[i] = 0.f;
  __syncthreads();
  const int wid = threadIdx.x >> 6, lane = threadIdx.x & 63;
  const int eg = lane / 9;          // edge-group within wave: 0..6 (lane 63 idle)
  const int k  = lane - eg * 9;     // frame component 0..8
  const bool active = lane < 63;
  const int p0 = base[b], p1 = base[b + 1];
  const int WSTEP = 7 * 8;          // 56 edges per wave per outer iter
  for (int start = p0 + wid * WSTEP; start < p1; start += 4 * WSTEP) {
    int pk[8];
    float v[8];
#pragma unroll
    for (int u = 0; u < 8; ++u) {
      int p = start + u * 7 + eg;
      pk[u] = (active && p < p1) ? sorted[p] : -1;   // sorted vals are >=0
    }
#pragma unroll
    for (int u = 0; u < 8; ++u)
      v[u] = (pk[u] >= 0) ? frames[(size_t)(pk[u] >> 6) * 9 + k] : 0.f;
#pragma unroll
    for (int u = 0; u < 8; ++u) {
      if (pk[u] >= 0) {
        int node = pk[u] & 63;
        atomicAdd(a + node * 11 + k, v[u]);
        if (k == 0) atomicAdd(a + node * 11 + 9, 1.0f);
      }
    }
  }
  __syncthreads();
  const int n0 = b << 6;
  for (int i = threadIdx.x; i < 64 * 10; i += 256) {
    int node = i / 10, kk = i - node * 10;
    int n = n0 + node;
    if (n < N_NODES) acc[(size_t)n * 10 + kk] = a[node * 11 + kk];
  }
}

// ---------------- prep: pre-swizzle Ws/Wg into MFMA B-fragment layout -------
__global__ __launch_bounds__(256) void prep_kernel(const float* __restrict__ Ws,
                                                   const float* __restrict__ Wg,
                                                   unsigned short* __restrict__ wsWs,
                                                   unsigned short* __restrict__ wsWg) {
  int idx = blockIdx.x * 256 + threadIdx.x;     // 80 blocks -> 20480 threads
  if (idx < 8 * 5 * 512) {                      // ((nt*5+kk)*64 + l)*8 + j
    int j = idx & 7, l = (idx >> 3) & 63, t = idx >> 9;
    int nt = t / 5, kk = t - nt * 5;
    int o = nt * 16 + (l & 15);
    int m = kk * 32 + ((l >> 4) << 3) + j;
    wsWs[idx] = (m < 153) ? f2bf(Ws[o * 153 + m]) : (unsigned short)0;
  }
  if (idx < 4 * 512) {                          // ((kk*64 + l)*8 + j)
    int j = idx & 7, l = (idx >> 3) & 63, kk = idx >> 9;
    int v = l & 15;
    int m = kk * 32 + ((l >> 4) << 3) + j;
    wsWg[idx] = f2bf(Wg[v * 128 + m]);
  }
}

// ---------------- node phase: MFMA for big matvec + gate --------------------
__global__ __launch_bounds__(256, 4) void node_kernel(
    const float* __restrict__ scalar_rep,   // [N][128]
    const float* __restrict__ vrep,         // [N][16][3]
    const float* __restrict__ Wd,           // [16][16]
    const float* __restrict__ Wf,           // [3][16]
    const float* __restrict__ bs,           // [128]
    const float* __restrict__ Wu,           // [16][16]
    const float* __restrict__ bg,           // [16]
    const unsigned short* __restrict__ wsWs,// pre-swizzled B-frags [8][5][64][8]
    const unsigned short* __restrict__ wsWg,// pre-swizzled B-frags [4][64][8]
    const float* __restrict__ acc,          // [N][10]
    float* __restrict__ out_s,              // [N][128]
    float* __restrict__ out_v) {            // [N][16][3]
  __shared__ alignas(16) unsigned short s_mergedb[16 * 168];  // bf16, pad->168
  __shared__ alignas(16) unsigned short s_sfb[16 * 136];      // bf16 silu
  __shared__ float s_vrep[16][48];
  __shared__ float s_vh[16][48];
  __shared__ float s_vdf[16][12];
  __shared__ float s_gate[16][16];
  __shared__ float s_WdT[256], s_WuT[256], s_Wf[48], s_bs[128], s_bg[16];

  const int tid = threadIdx.x;
  {
    int a = tid >> 4, b = tid & 15;
    s_WdT[b * 16 + a] = Wd[tid];
    s_WuT[b * 16 + a] = Wu[tid];
  }
  if (tid < 48) s_Wf[tid] = Wf[tid];
  if (tid < 128) s_bs[tid] = bs[tid];
  if (tid < 16) s_bg[tid] = bg[tid];
  if (tid < 240) {                       // zero merged pad cols 153..167
    int r = tid / 15, c = 153 + tid % 15;
    s_mergedb[r * 168 + c] = 0;
  }

  const int i4 = tid >> 4, j4 = tid & 15;
  const int wid = tid >> 6, lane = tid & 63;
  const int lr = lane & 15, lk = lane >> 4;

  const float4* scalar4 = (const float4*)scalar_rep;
  const float4* vrep4 = (const float4*)vrep;

  for (int g = blockIdx.x; g < N_NODES / NB; g += gridDim.x) {
    const int n0 = g * NB;
    __syncthreads();   // previous iteration consumers done
    // stage scalar_rep -> bf16 merged[.,0:128]
    for (int idx = tid; idx < 512; idx += 256) {
      float4 v = scalar4[(size_t)n0 * 32 + idx];
      int r = idx >> 5, c4 = idx & 31;
      unsigned short* d = s_mergedb + r * 168 + c4 * 4;
      d[0] = f2bf(v.x); d[1] = f2bf(v.y); d[2] = f2bf(v.z); d[3] = f2bf(v.w);
    }
    // stage vector_rep f32
    for (int idx = tid; idx < 192; idx += 256)
      ((float4*)s_vrep)[idx] = vrep4[(size_t)n0 * 12 + idx];
    __syncthreads();
    // vh + vnorm
    {
      float a0 = 0.f, a1 = 0.f, a2 = 0.f;
#pragma unroll
      for (int v = 0; v < 16; ++v) {
        float w = s_WdT[v * 16 + j4];
        a0 += s_vrep[i4][v * 3 + 0] * w;
        a1 += s_vrep[i4][v * 3 + 1] * w;
        a2 += s_vrep[i4][v * 3 + 2] * w;
      }
      s_vh[i4][j4]      = a0;
      s_vh[i4][16 + j4] = a1;
      s_vh[i4][32 + j4] = a2;
      s_mergedb[i4 * 168 + 128 + j4] = f2bf(sqrtf(a0 * a0 + a1 * a1 + a2 * a2 + EPSV));
    }
    // vdf
    if (j4 < 9) {
      int t = j4 / 3, f = j4 - t * 3;
      float a = 0.f;
#pragma unroll
      for (int v = 0; v < 16; ++v)
        a += s_vrep[i4][v * 3 + t] * s_Wf[f * 16 + v];
      s_vdf[i4][j4] = a;
    }
    __syncthreads();
    // scalar_hidden -> merged[.,144:153]
    if (j4 < 9) {
      int f = j4 / 3, s = j4 - f * 3;
      const float* a = acc + (size_t)(n0 + i4) * 10;
      float c = fmaxf(a[9], 1.0f);
      float sum = a[s * 3 + 0] * s_vdf[i4][0 + f] +
                  a[s * 3 + 1] * s_vdf[i4][3 + f] +
                  a[s * 3 + 2] * s_vdf[i4][6 + f];
      s_mergedb[i4 * 168 + 144 + j4] = f2bf(sum / c);
    }
    __syncthreads();
    // big MFMA: merged[16x160] @ WsT[160x128]; wave wid owns N-tiles 2w,2w+1
    {
      const int nt0 = wid * 2;
      short8 afrag[5];
#pragma unroll
      for (int kk = 0; kk < 5; ++kk)
        afrag[kk] = *(const short8*)(s_mergedb + lr * 168 + kk * 32 + lk * 8);
      float b0v = s_bs[nt0 * 16 + lr], b1v = s_bs[nt0 * 16 + 16 + lr];
      f32x4 acc0 = {b0v, b0v, b0v, b0v};
      f32x4 acc1 = {b1v, b1v, b1v, b1v};
#pragma unroll
      for (int kk = 0; kk < 5; ++kk) {
        short8 bf0 = *(const short8*)(wsWs + (((nt0 * 5 + kk) << 6) + lane) * 8);
        short8 bf1 = *(const short8*)(wsWs + ((((nt0 + 1) * 5 + kk) << 6) + lane) * 8);
        acc0 = __builtin_amdgcn_mfma_f32_16x16x32_bf16(afrag[kk], bf0, acc0, 0, 0, 0);
        acc1 = __builtin_amdgcn_mfma_f32_16x16x32_bf16(afrag[kk], bf1, acc1, 0, 0, 0);
      }
#pragma unroll
      for (int j = 0; j < 4; ++j) {
        int node = lk * 4 + j;
        float x0 = acc0[j];
        float sf0 = x0 / (1.0f + __expf(-x0));
        out_s[(size_t)(n0 + node) * 128 + nt0 * 16 + lr] = sf0;
        s_sfb[node * 136 + nt0 * 16 + lr] = f2bf(sf0);
        float x1 = acc1[j];
        float sf1 = x1 / (1.0f + __expf(-x1));
        out_s[(size_t)(n0 + node) * 128 + nt0 * 16 + 16 + lr] = sf1;
        s_sfb[node * 136 + nt0 * 16 + 16 + lr] = f2bf(sf1);
      }
    }
    __syncthreads();
    // gate MFMA on wave 0: sf[16x128] @ WgT[128x16]
    if (wid == 0) {
      float gb = s_bg[lr];
      f32x4 gacc = {gb, gb, gb, gb};
#pragma unroll
      for (int kk = 0; kk < 4; ++kk) {
        short8 ga = *(const short8*)(s_sfb + lr * 136 + kk * 32 + lk * 8);
        short8 gw = *(const short8*)(wsWg + (((kk << 6) + lane) * 8));
        gacc = __builtin_amdgcn_mfma_f32_16x16x32_bf16(ga, gw, gacc, 0, 0, 0);
      }
#pragma unroll
      for (int j = 0; j < 4; ++j) {
        int node = lk * 4 + j;
        s_gate[node][lr] = 1.0f / (1.0f + __expf(-gacc[j]));
      }
    }
    __syncthreads();
    // v_up + gated output
    {
      float b0 = 0.f, b1 = 0.f, b2 = 0.f;
#pragma unroll
      for (int h = 0; h < 16; ++h) {
        float w = s_WuT[h * 16 + j4];
        b0 += s_vh[i4][h]      * w;
        b1 += s_vh[i4][16 + h] * w;
        b2 += s_vh[i4][32 + h] * w;
      }
      float gt = s_gate[i4][j4];
      size_t basep = (size_t)(n0 + i4) * 48 + (size_t)j4 * 3;
      out_v[basep + 0] = b0 * gt;
      out_v[basep + 1] = b1 * gt;
      out_v[basep + 2] = b2 * gt;
    }
  }
}

extern "C" void kernel_launch(void* const* d_in, const int* in_sizes, int n_in,
                              void* d_out, int out_size, void* d_ws, size_t ws_size,
                              hipStream_t stream) {
  const float* scalar_rep = (const float*)d_in[0];
  const float* vector_rep = (const float*)d_in[1];
  const float* frames     = (const float*)d_in[2];
  const float* W_down     = (const float*)d_in[3];
  const float* W_frames   = (const float*)d_in[4];
  const float* W_scalar   = (const float*)d_in[5];
  const float* b_scalar   = (const float*)d_in[6];
  const float* W_up       = (const float*)d_in[7];
  const float* W_gate     = (const float*)d_in[8];
  const float* b_gate     = (const float*)d_in[9];
  const int*   edge_index = (const int*)d_in[10];   // [2][E], row = first E

  float* out = (float*)d_out;

  // workspace layout (all regions multiples of 16 ints -> 16B aligned)
  int* ws = (int*)d_ws;
  int*   hist   = ws;                                  // 512*1563 = 800256
  int*   total  = hist + 800256;                       // 1600
  int*   base   = total + 1600;                        // 1600
  int*   sorted = base + 1600;                         // 3200000
  float* acc    = (float*)(sorted + 3200000);          // 1000000 floats
  unsigned short* wsWs = (unsigned short*)(acc + 1000000);  // 20480 bf16
  unsigned short* wsWg = wsWs + 20480;                      // 2048 bf16

  prep_kernel   <<<80,     256, 0, stream>>>(W_scalar, W_gate, wsWs, wsWg);
  hist_kernel   <<<NCHUNK, 256, 0, stream>>>(edge_index, hist);
  scanc_kernel  <<<NBUCK,  256, 0, stream>>>(hist, total);
  scanb_kernel  <<<1,      256, 0, stream>>>(total, base);
  scatter_kernel<<<NCHUNK, 256, 0, stream>>>(edge_index, hist, base, sorted);
  reduce_kernel <<<NBUCK,  256, 0, stream>>>(sorted, base, frames, acc);

  node_kernel<<<768, 256, 0, stream>>>(
      scalar_rep, vector_rep, W_down, W_frames, b_scalar,
      W_up, b_gate, wsWs, wsWg, acc,
      out, out + (size_t)N_NODES * 128);
}